// Round 13
// baseline (273.383 us; speedup 1.0000x reference)
//
#include <hip/hip_runtime.h>
#include <math.h>

// B=8, C=64, T=128, E=256, 4E=1024, TYPE_NUM=40, NF=128
// v19 = v18 + U-materialization: Ubf[bc][kc][trow][g] (67MB bf16, granule
//   pre-swizzled like Whbf_t) computed once in cvt; attn_u loads U via
//   global_load_lds instead of recomputing it 8x per c-pair (the 57% VALU).
//   This REMOVES ~40 live VGPRs from the attn loop (spill risk runs the safe
//   direction). Runtime ws_size guard: if workspace < 81MB, launch v18 path.
//   h_pre[b,c,t,:] = Apre[c,:] + Bpre[b*128+t,:] + [|q-ctx|, q*ctx] @ Wh[:,512:]^T

typedef __bf16 bf16x8 __attribute__((ext_vector_type(8)));
typedef float  f32x4  __attribute__((ext_vector_type(4)));

__device__ __forceinline__ float ftanh(float v) {
    float t = __expf(2.f * v);
    return 1.f - 2.f * __builtin_amdgcn_rcpf(t + 1.f);
}

// async 16B/lane global->LDS copy: lds dest must be wave-uniform; lane i lands
// at l + i*16B. g is per-lane.
__device__ __forceinline__ void gld_lds16(const __bf16* g, __bf16* l) {
    __builtin_amdgcn_global_load_lds(
        (const __attribute__((address_space(1))) void*)g,
        (__attribute__((address_space(3))) void*)l, 16, 0, 0);
}

__device__ __forceinline__ bf16x8 cvt8(float4 f0, float4 f1) {
    bf16x8 u;
    u[0] = (__bf16)f0.x; u[1] = (__bf16)f0.y; u[2] = (__bf16)f0.z; u[3] = (__bf16)f0.w;
    u[4] = (__bf16)f1.x; u[5] = (__bf16)f1.y; u[6] = (__bf16)f1.z; u[7] = (__bf16)f1.w;
    return u;
}

// ---------------- cvt + fused Apre GEMM + fused Bpre GEMM + U-materialize -------
// blocks 0-15:     Apre = q @ Wh^T + bh  (fp32 exact; M=64,N=1024,K=256)
// blocks 16-271:   Bpre = bf16(ctx) @ bf16(Wh[:,256:512])^T (inline cvt staging)
// blocks 272-2907: conversions / zero-init (idx-driven)
// blocks >=2908:   Ubf materialize (only when launched with grid 4956)
__global__ __launch_bounds__(256) void cvt_kernel(
    const float* __restrict__ Wh, const float* __restrict__ Wl,
    const float* __restrict__ ctx,
    const float* __restrict__ cw0, const float* __restrict__ cw1,
    const float* __restrict__ cw2,
    const float* __restrict__ q, const float* __restrict__ bh,
    float* __restrict__ Apre, float* __restrict__ x, float* __restrict__ Bpre,
    __bf16* __restrict__ Whbf, __bf16* __restrict__ Whbf_t,
    __bf16* __restrict__ Wlbf,
    float* __restrict__ wt0, float* __restrict__ wt1,
    float* __restrict__ wt2, float* __restrict__ gsc,
    float* __restrict__ cnn, __bf16* __restrict__ Ubf)
{
    __shared__ __align__(16) char smem[18432];
    const int bx = blockIdx.x;
    const int tid = threadIdx.x;

    if (bx >= 2908) {
        // ---- Ubf materialize: thread = (bc, trow, kg); 524288 threads ----
        int idx2 = (bx - 2908) * 256 + tid;      // < 524288
        int bc = idx2 >> 10;                     // 0..511
        int rem = idx2 & 1023;
        int trow = rem >> 3, kg = rem & 7;
        int b = bc >> 6, c = bc & 63;
        int gs = kg ^ (trow & 7);
#pragma unroll
        for (int ec = 0; ec < 4; ++ec) {
            int eb = ec * 64 + kg * 8;
            const float* cp = ctx + (size_t)(b * 128 + trow) * 256 + eb;
            float4 c0 = *reinterpret_cast<const float4*>(cp);
            float4 c1 = *reinterpret_cast<const float4*>(cp + 4);
            const float* qp = q + (size_t)c * 256 + eb;
            float4 q0 = *reinterpret_cast<const float4*>(qp);
            float4 q1 = *reinterpret_cast<const float4*>(qp + 4);
            float cv[8] = {c0.x, c0.y, c0.z, c0.w, c1.x, c1.y, c1.z, c1.w};
            float qv[8] = {q0.x, q0.y, q0.z, q0.w, q1.x, q1.y, q1.z, q1.w};
            bf16x8 ua, um;
#pragma unroll
            for (int i = 0; i < 8; ++i) {
                ua[i] = (__bf16)fabsf(qv[i] - cv[i]);
                um[i] = (__bf16)(qv[i] * cv[i]);
            }
            *reinterpret_cast<bf16x8*>(
                Ubf + (((size_t)(bc * 8 + ec) * 128 + trow) * 8 + gs) * 8) = ua;
            *reinterpret_cast<bf16x8*>(
                Ubf + (((size_t)(bc * 8 + 4 + ec) * 128 + trow) * 8 + gs) * 8) = um;
        }
        return;
    }

    if (bx < 16) {
        // ---- Apre GEMM: C[m,n] = sum_k q[m,k]*Wh[n,k] + bh[n] ----
        float (*As)[68] = reinterpret_cast<float(*)[68]>(smem);
        float (*Bs)[68] = reinterpret_cast<float(*)[68]>(smem + 4352);
        const int n0 = bx * 64;
        const int tm = tid >> 4, tn = tid & 15;
        const int lr = tid >> 2;
        const int lc = (tid & 3) * 4;

        float acc[4][4];
#pragma unroll
        for (int i = 0; i < 4; ++i)
#pragma unroll
            for (int j = 0; j < 4; ++j) acc[i][j] = 0.f;

        for (int k0 = 0; k0 < 256; k0 += 16) {
            float4 av = *reinterpret_cast<const float4*>(q + (size_t)lr * 256 + k0 + lc);
            float4 bv = *reinterpret_cast<const float4*>(Wh + (size_t)(n0 + lr) * 1024 + k0 + lc);
            As[lc + 0][lr] = av.x; As[lc + 1][lr] = av.y; As[lc + 2][lr] = av.z; As[lc + 3][lr] = av.w;
            Bs[lc + 0][lr] = bv.x; Bs[lc + 1][lr] = bv.y; Bs[lc + 2][lr] = bv.z; Bs[lc + 3][lr] = bv.w;
            __syncthreads();
#pragma unroll
            for (int kk = 0; kk < 16; ++kk) {
                float4 a = *reinterpret_cast<const float4*>(&As[kk][tm * 4]);
                float4 b = *reinterpret_cast<const float4*>(&Bs[kk][tn * 4]);
                float ar[4] = {a.x, a.y, a.z, a.w};
                float br[4] = {b.x, b.y, b.z, b.w};
#pragma unroll
                for (int i = 0; i < 4; ++i)
#pragma unroll
                    for (int j = 0; j < 4; ++j) acc[i][j] += ar[i] * br[j];
            }
            __syncthreads();
        }

#pragma unroll
        for (int i = 0; i < 4; ++i) {
            int m = tm * 4 + i;
            float vals[4];
#pragma unroll
            for (int j = 0; j < 4; ++j) vals[j] = acc[i][j] + bh[n0 + tn * 4 + j];
            float4 o; o.x = vals[0]; o.y = vals[1]; o.z = vals[2]; o.w = vals[3];
            *reinterpret_cast<float4*>(Apre + (size_t)m * 1024 + n0 + tn * 4) = o;
        }
        return;
    }

    if (bx < 272) {
        // ---- Bpre GEMM (MFMA, inline fp32->bf16 staging) ----
        __bf16* As = reinterpret_cast<__bf16*>(smem);
        __bf16* Bs = As + 64 * 72;
        const int bid = bx - 16;
        const int m0 = (bid >> 4) * 64, n0 = (bid & 15) * 64;
        const int wave = tid >> 6, lane = tid & 63;
        const int w0 = wave >> 1, w1 = wave & 1;
        const int l15 = lane & 15, quad = lane >> 4;

        f32x4 acc[2][2];
#pragma unroll
        for (int mi = 0; mi < 2; ++mi)
#pragma unroll
            for (int ni = 0; ni < 2; ++ni) acc[mi][ni] = (f32x4){0.f, 0.f, 0.f, 0.f};

        for (int k0 = 0; k0 < 256; k0 += 64) {
            __syncthreads();
#pragma unroll
            for (int it = 0; it < 2; ++it) {
                int idx = tid + it * 256;
                int row = idx >> 3, kgi = idx & 7;
                const float* sa = ctx + (size_t)(m0 + row) * 256 + k0 + kgi * 8;
                float4 a0 = *reinterpret_cast<const float4*>(sa);
                float4 a1 = *reinterpret_cast<const float4*>(sa + 4);
                *reinterpret_cast<bf16x8*>(&As[row * 72 + kgi * 8]) = cvt8(a0, a1);
                const float* sb = Wh + (size_t)(n0 + row) * 1024 + 256 + k0 + kgi * 8;
                float4 b0 = *reinterpret_cast<const float4*>(sb);
                float4 b1 = *reinterpret_cast<const float4*>(sb + 4);
                *reinterpret_cast<bf16x8*>(&Bs[row * 72 + kgi * 8]) = cvt8(b0, b1);
            }
            __syncthreads();
#pragma unroll
            for (int ks = 0; ks < 2; ++ks) {
                bf16x8 a[2], bb[2];
#pragma unroll
                for (int mi = 0; mi < 2; ++mi)
                    a[mi] = *reinterpret_cast<const bf16x8*>(
                        &As[(w0 * 32 + mi * 16 + l15) * 72 + ks * 32 + quad * 8]);
#pragma unroll
                for (int ni = 0; ni < 2; ++ni)
                    bb[ni] = *reinterpret_cast<const bf16x8*>(
                        &Bs[(w1 * 32 + ni * 16 + l15) * 72 + ks * 32 + quad * 8]);
#pragma unroll
                for (int mi = 0; mi < 2; ++mi)
#pragma unroll
                    for (int ni = 0; ni < 2; ++ni)
                        acc[mi][ni] = __builtin_amdgcn_mfma_f32_16x16x32_bf16(
                            a[mi], bb[ni], acc[mi][ni], 0, 0, 0);
            }
        }

#pragma unroll
        for (int mi = 0; mi < 2; ++mi)
#pragma unroll
            for (int ni = 0; ni < 2; ++ni) {
                int col = n0 + w1 * 32 + ni * 16 + l15;
#pragma unroll
                for (int r = 0; r < 4; ++r) {
                    int row = m0 + w0 * 32 + mi * 16 + quad * 4 + r;
                    Bpre[(size_t)row * 1024 + col] = acc[mi][ni][r];
                }
            }
        return;
    }

    int idx = (bx - 272) * 256 + tid;            // < 674816
    if (idx < 131072) {                          // Whbf flat
        const float* s = Wh + (size_t)idx * 8;
        float4 f0 = *reinterpret_cast<const float4*>(s);
        float4 f1 = *reinterpret_cast<const float4*>(s + 4);
        *reinterpret_cast<bf16x8*>(Whbf + (size_t)idx * 8) = cvt8(f0, f1);
        return;
    }
    if (idx < 196608) {                          // Whbf_t 65536 granules
        int di = idx - 131072;
        int ng = di >> 13, kc = (di >> 10) & 7;
        int row = (di >> 3) & 127, kgp = di & 7;
        int kg = kgp ^ (row & 7);
        const float* s = Wh + (size_t)(ng * 128 + row) * 1024 + 512 + kc * 64 + kg * 8;
        float4 f0 = *reinterpret_cast<const float4*>(s);
        float4 f1 = *reinterpret_cast<const float4*>(s + 4);
        *reinterpret_cast<bf16x8*>(Whbf_t + (size_t)di * 8) = cvt8(f0, f1);
        return;
    }
    if (idx < 229376) {                          // Wlbf 32768 granules
        int di = idx - 196608;
        const float* s = Wl + (size_t)di * 8;
        float4 f0 = *reinterpret_cast<const float4*>(s);
        float4 f1 = *reinterpret_cast<const float4*>(s + 4);
        *reinterpret_cast<bf16x8*>(Wlbf + (size_t)di * 8) = cvt8(f0, f1);
        return;
    }
    if (idx < 393216) {
        int j = idx - 229376; int f = j & 127, rest = j >> 7;
        int i = rest % 5, e = rest / 5;
        wt0[j] = cw0[(size_t)(f * 256 + e) * 5 + i]; return;
    }
    if (idx < 524288) {
        int j = idx - 393216; int f = j & 127, rest = j >> 7;
        int i = rest & 3, e = rest >> 2;
        wt1[j] = cw1[(size_t)(f * 256 + e) * 4 + i]; return;
    }
    if (idx < 622592) {
        int j = idx - 524288; int f = j & 127, rest = j >> 7;
        int i = rest % 3, e = rest / 3;
        wt2[j] = cw2[(size_t)(f * 256 + e) * 3 + i]; return;
    }
    if (idx < 638976) {                          // gsc zero (float4)
        int di = idx - 622592;
        reinterpret_cast<float4*>(gsc)[di] = (float4){0.f, 0.f, 0.f, 0.f};
        return;
    }
    if (idx < 642048) { cnn[idx - 638976] = 0.f; return; }
    if (idx < 674816) {                          // x zero (float4)
        int di = idx - 642048;
        reinterpret_cast<float4*>(x)[di] = (float4){0.f, 0.f, 0.f, 0.f};
    }
}

// ---------------- attn v19 MFMA: all-async (U from Ubf, W from Whbf_t) ----------
__global__ __launch_bounds__(512, 4) void attn_mfma_u_kernel(
    const __bf16* __restrict__ Ubf,     // [512bc][8kc][128][8g] swizzled granules
    const __bf16* __restrict__ Whbf_t,  // tiled+swizzled bf16 W (abs+mul cols)
    const float* __restrict__ Wv,       // [1024]
    const float* __restrict__ Apre,     // [64][1024]  (q-part + b_hidden)
    const float* __restrict__ Bpre,     // [1024][1024] (ctx-part)
    float* __restrict__ gsc)            // [512][128] pre-zeroed
{
    __shared__ __bf16 Us[256 * 64];     // rows 0-127: c0, 128-255: c0+1
    __shared__ __bf16 Ws[128 * 64];
    __shared__ float sc[256];

    const int tid = threadIdx.x;
    const int cpair = blockIdx.x >> 3, ng = blockIdx.x & 7;
    const int b = cpair >> 5, c0 = (cpair & 31) * 2;
    const int wave = tid >> 6, lane = tid & 63;
    const int w1 = wave & 1, w0 = wave >> 1;     // w0: M quarter 0..3
    const int m0 = w0 * 64;
    const int l15 = lane & 15, quad = lane >> 4;
    const int swz = l15 & 7;            // row&7 for all our frag rows

    if (tid < 256) sc[tid] = 0.f;
    __syncthreads();

    const __bf16* ubase = Ubf + (size_t)(b * 64 + c0) * 65536;   // 8 kc * 8192

    f32x4 acc[4][4];
#pragma unroll
    for (int mi = 0; mi < 4; ++mi)
#pragma unroll
        for (int ni = 0; ni < 4; ++ni) acc[mi][ni] = (f32x4){0.f, 0.f, 0.f, 0.f};

    for (int kc = 0; kc < 8; ++kc) {
        __syncthreads();            // prior MFMA reads done before overwrite
        // ---- W tile: 1024 granules async, 128 per wave ----
        const __bf16* wtile = Whbf_t + (size_t)(ng * 8 + kc) * 8192;
        // ---- U tiles: c0 and c0+1, 1024 granules each ----
        const __bf16* ut0 = ubase + (size_t)kc * 8192;
        const __bf16* ut1 = ut0 + 65536;
#pragma unroll
        for (int it = 0; it < 2; ++it) {
            int gidx = wave * 128 + it * 64;   // + lane inside
            gld_lds16(wtile + (size_t)(gidx + lane) * 8, &Ws[gidx * 8]);
            gld_lds16(ut0 + (size_t)(gidx + lane) * 8, &Us[gidx * 8]);
            gld_lds16(ut1 + (size_t)(gidx + lane) * 8, &Us[8192 + gidx * 8]);
        }
        __syncthreads();            // drains vmcnt (async)
        // ---- MFMA on staged chunk ----
#pragma unroll
        for (int ks = 0; ks < 2; ++ks) {
            const int c8 = (((ks * 4 + quad) ^ swz)) * 8;
            bf16x8 a[4], bfr[4];
#pragma unroll
            for (int mi = 0; mi < 4; ++mi)
                a[mi] = *reinterpret_cast<const bf16x8*>(
                    &Us[(m0 + mi * 16 + l15) * 64 + c8]);
#pragma unroll
            for (int ni = 0; ni < 4; ++ni)
                bfr[ni] = *reinterpret_cast<const bf16x8*>(
                    &Ws[(w1 * 64 + ni * 16 + l15) * 64 + c8]);
#pragma unroll
            for (int mi = 0; mi < 4; ++mi)
#pragma unroll
                for (int ni = 0; ni < 4; ++ni)
                    acc[mi][ni] = __builtin_amdgcn_mfma_f32_16x16x32_bf16(
                        a[mi], bfr[ni], acc[mi][ni], 0, 0, 0);
        }
    }

    // ---- epilogue: h = ftanh(acc + Apre + Bpre), partial score = h . Wv ----
    const int jcol = ng * 128 + w1 * 64 + l15;
    const int c = c0 + (w0 >> 1);
    float av[4], wv[4];
#pragma unroll
    for (int ni = 0; ni < 4; ++ni) {
        av[ni] = Apre[(size_t)c * 1024 + jcol + ni * 16];
        wv[ni] = Wv[jcol + ni * 16];
    }
#pragma unroll
    for (int mi = 0; mi < 4; ++mi) {
        const int tb = (w0 & 1) * 64 + mi * 16 + quad * 4;   // t within 0..127
        float p[4];
#pragma unroll
        for (int r = 0; r < 4; ++r) {
            const float* bp = Bpre + (size_t)(b * 128 + tb + r) * 1024 + jcol;
            float s = 0.f;
#pragma unroll
            for (int ni = 0; ni < 4; ++ni)
                s += ftanh(acc[mi][ni][r] + av[ni] + bp[ni * 16]) * wv[ni];
            p[r] = s;
        }
#pragma unroll
        for (int off = 1; off < 16; off <<= 1)
#pragma unroll
            for (int r = 0; r < 4; ++r) p[r] += __shfl_xor(p[r], off, 16);
        if (l15 == 0) {
#pragma unroll
            for (int r = 0; r < 4; ++r)
                atomicAdd(&sc[(w0 >> 1) * 128 + tb + r], p[r]);
        }
    }
    __syncthreads();

    // flush partial scores (8 ng blocks add into gsc)
    if (tid < 256) atomicAdd(&gsc[(size_t)(b * 64 + c0) * 128 + tid], sc[tid]);
}

// ---------------- attn v12 MFMA (FROZEN fallback, verbatim v18) ----------------
__global__ __launch_bounds__(512, 4) void attn_mfma_kernel(
    const float* __restrict__ q,        // [64][256]
    const float* __restrict__ ctx,      // [8][128][256] fp32
    const __bf16* __restrict__ Whbf_t,  // tiled+swizzled bf16 W (abs+mul cols)
    const float* __restrict__ Wv,       // [1024]
    const float* __restrict__ Apre,     // [64][1024]  (q-part + b_hidden)
    const float* __restrict__ Bpre,     // [1024][1024] (ctx-part)
    float* __restrict__ gsc)            // [512][128] pre-zeroed
{
    __shared__ __bf16 Us[256 * 64];     // rows 0-127: c0, 128-255: c0+1
    __shared__ __bf16 Ws[128 * 64];
    __shared__ float qc[512];
    __shared__ float sc[256];

    const int tid = threadIdx.x;
    const int cpair = blockIdx.x >> 3, ng = blockIdx.x & 7;
    const int b = cpair >> 5, c0 = (cpair & 31) * 2;
    const int wave = tid >> 6, lane = tid & 63;
    const int w1 = wave & 1, w0 = wave >> 1;     // w0: M quarter 0..3
    const int m0 = w0 * 64;
    const int l15 = lane & 15, quad = lane >> 4;
    const int swz = l15 & 7;            // row&7 for all our frag rows
    const int kg = tid & 7;             // granule slot: iteration-invariant

    qc[tid] = q[(size_t)(c0 + (tid >> 8)) * 256 + (tid & 255)];
    if (tid < 256) sc[tid] = 0.f;
    __syncthreads();

    f32x4 acc[4][4];
#pragma unroll
    for (int mi = 0; mi < 4; ++mi)
#pragma unroll
        for (int ni = 0; ni < 4; ++ni) acc[mi][ni] = (f32x4){0.f, 0.f, 0.f, 0.f};

    for (int kc = 0; kc < 8; ++kc) {
        // ---- U precompute in regs (overlaps previous MFMA) ----
        const bool isabs = (kc < 4);         // kc 0-3: |q-ctx|, 4-7: q*ctx
        const int e0 = (kc & 3) * 64;
        const int eb = e0 + kg * 8;
        float qA[8], qB[8];
#pragma unroll
        for (int i = 0; i < 8; ++i) { qA[i] = qc[eb + i]; qB[i] = qc[256 + eb + i]; }
        bf16x8 u0[2], u1[2];
#pragma unroll
        for (int it = 0; it < 2; ++it) {
            const int trow = it * 64 + (tid >> 3);   // 0..127
            const float* cp = ctx + (size_t)(b * 128 + trow) * 256 + eb;
            float4 cl0 = *reinterpret_cast<const float4*>(cp);
            float4 cl1 = *reinterpret_cast<const float4*>(cp + 4);
            float cv[8] = {cl0.x, cl0.y, cl0.z, cl0.w, cl1.x, cl1.y, cl1.z, cl1.w};
#pragma unroll
            for (int i = 0; i < 8; ++i) {
                u0[it][i] = (__bf16)(isabs ? fabsf(qA[i] - cv[i]) : qA[i] * cv[i]);
                u1[it][i] = (__bf16)(isabs ? fabsf(qB[i] - cv[i]) : qB[i] * cv[i]);
            }
        }
        __syncthreads();            // prior MFMA reads done before overwrite
        // ---- W tile: 1024 granules async, 128 per wave ----
        const __bf16* wtile = Whbf_t + (size_t)(ng * 8 + kc) * 8192;
#pragma unroll
        for (int it = 0; it < 2; ++it) {
            int gidx = wave * 128 + it * 64;   // + lane inside
            gld_lds16(wtile + (size_t)(gidx + lane) * 8, &Ws[gidx * 8]);
        }
        // ---- U tile: write both c's granules ----
#pragma unroll
        for (int it = 0; it < 2; ++it) {
            const int trow = it * 64 + (tid >> 3);
            const int off = (kg ^ (trow & 7)) * 8;
            *reinterpret_cast<bf16x8*>(&Us[trow * 64 + off]) = u0[it];
            *reinterpret_cast<bf16x8*>(&Us[(trow + 128) * 64 + off]) = u1[it];
        }
        __syncthreads();            // drains vmcnt (async) + lgkm (writes)
        // ---- MFMA on staged chunk ----
#pragma unroll
        for (int ks = 0; ks < 2; ++ks) {
            const int c8 = (((ks * 4 + quad) ^ swz)) * 8;
            bf16x8 a[4], bfr[4];
#pragma unroll
            for (int mi = 0; mi < 4; ++mi)
                a[mi] = *reinterpret_cast<const bf16x8*>(
                    &Us[(m0 + mi * 16 + l15) * 64 + c8]);
#pragma unroll
            for (int ni = 0; ni < 4; ++ni)
                bfr[ni] = *reinterpret_cast<const bf16x8*>(
                    &Ws[(w1 * 64 + ni * 16 + l15) * 64 + c8]);
#pragma unroll
            for (int mi = 0; mi < 4; ++mi)
#pragma unroll
                for (int ni = 0; ni < 4; ++ni)
                    acc[mi][ni] = __builtin_amdgcn_mfma_f32_16x16x32_bf16(
                        a[mi], bfr[ni], acc[mi][ni], 0, 0, 0);
        }
    }

    // ---- epilogue: h = ftanh(acc + Apre + Bpre), partial score = h . Wv ----
    const int jcol = ng * 128 + w1 * 64 + l15;
    const int c = c0 + (w0 >> 1);
    float av[4], wv[4];
#pragma unroll
    for (int ni = 0; ni < 4; ++ni) {
        av[ni] = Apre[(size_t)c * 1024 + jcol + ni * 16];
        wv[ni] = Wv[jcol + ni * 16];
    }
#pragma unroll
    for (int mi = 0; mi < 4; ++mi) {
        const int tb = (w0 & 1) * 64 + mi * 16 + quad * 4;   // t within 0..127
        float p[4];
#pragma unroll
        for (int r = 0; r < 4; ++r) {
            const float* bp = Bpre + (size_t)(b * 128 + tb + r) * 1024 + jcol;
            float s = 0.f;
#pragma unroll
            for (int ni = 0; ni < 4; ++ni)
                s += ftanh(acc[mi][ni][r] + av[ni] + bp[ni * 16]) * wv[ni];
            p[r] = s;
        }
#pragma unroll
        for (int off = 1; off < 16; off <<= 1)
#pragma unroll
            for (int r = 0; r < 4; ++r) p[r] += __shfl_xor(p[r], off, 16);
        if (l15 == 0) {
#pragma unroll
            for (int r = 0; r < 4; ++r)
                atomicAdd(&sc[(w0 >> 1) * 128 + tb + r], p[r]);
        }
    }
    __syncthreads();

    // flush partial scores (8 ng blocks add into gsc)
    if (tid < 256) atomicAdd(&gsc[(size_t)(b * 64 + c0) * 128 + tid], sc[tid]);
}

// ---------------- attn tail: softmax + g, fused feat2 output + h2pre zero ------
__global__ __launch_bounds__(256) void attn_tail_kernel(
    const float* __restrict__ ctx, const int* __restrict__ mask,
    const float* __restrict__ bv, const float* __restrict__ gsc,
    const float* __restrict__ q, __bf16* __restrict__ feat2,
    float* __restrict__ h2pre)
{
    __shared__ float sc[128];
    __shared__ float red;
    const int tid = threadIdx.x;
    const int bc = blockIdx.x, b = bc >> 6, c = bc & 63;

    // zero h2pre for the K-split atomic GEMM (512*256 float4 = 524288 floats)
    reinterpret_cast<float4*>(h2pre)[(size_t)bc * 256 + tid] =
        (float4){0.f, 0.f, 0.f, 0.f};

    if (tid < 128) {
        float s = gsc[(size_t)bc * 128 + tid] + bv[0];
        if (mask[b * 128 + tid] < 1) s = -1e10f;
        sc[tid] = s;
    }
    __syncthreads();
    if (tid < 64) {
        float m = fmaxf(sc[tid], sc[tid + 64]);
        for (int off = 32; off; off >>= 1) m = fmaxf(m, __shfl_xor(m, off, 64));
        if (tid == 0) red = m;
    }
    __syncthreads();
    const float mx = red;
    if (tid < 128) sc[tid] = __expf(sc[tid] - mx);
    __syncthreads();
    if (tid < 64) {
        float s = sc[tid] + sc[tid + 64];
        for (int off = 32; off; off >>= 1) s += __shfl_xor(s, off, 64);
        if (tid == 0) red = s;
    }
    __syncthreads();
    const float inv = 1.f / red;

    float gv = 0.f;
#pragma unroll 16
    for (int t = 0; t < 128; ++t) gv += sc[t] * ctx[(size_t)(b * 128 + t) * 256 + tid];
    gv *= inv;
    const float qv = q[(size_t)c * 256 + tid];
    __bf16* o = feat2 + (size_t)bc * 768 + tid;
    o[0]   = (__bf16)gv;
    o[256] = (__bf16)fabsf(qv - gv);
    o[512] = (__bf16)(qv * gv);
}

// ---------------- bf16 MFMA GEMM: C = act(A @ B^T + bias), 64x64 tile ----------------
// BMODE 0: bias[col]; BMODE 1: bias[(row&63)*1024 + col]; BMODE 2: no bias
// ATOMIC 1: K split over blockIdx.z; atomicAdd into fp32 Cout (pre-zeroed);
//           bias added by z==0 only. Requires OUTBF=0, ACT=0.
// ATANH 1:  A is fp32; staging applies ftanh then converts to bf16.
template <int ACT, int OUTBF, int BMODE, int ATOMIC, int ATANH>
__global__ __launch_bounds__(256) void mfma_gemm_kernel(
    const void* __restrict__ A, int lda,
    const __bf16* __restrict__ B, int ldb,
    const float* __restrict__ bias, void* __restrict__ Cout,
    int K, int ldc)
{
    __shared__ __bf16 As[64 * 72];
    __shared__ __bf16 Bs[64 * 72];
    const int tid = threadIdx.x;
    const int wave = tid >> 6, lane = tid & 63;
    const int w0 = wave >> 1, w1 = wave & 1;
    const int l15 = lane & 15, quad = lane >> 4;
    const int m0 = blockIdx.y * 64, n0 = blockIdx.x * 64;

    int kbeg = 0, kend = K;
    if (ATOMIC) {
        int kchunk = K / gridDim.z;
        kbeg = blockIdx.z * kchunk;
        kend = kbeg + kchunk;
    }

    f32x4 acc[2][2];
#pragma unroll
    for (int mi = 0; mi < 2; ++mi)
#pragma unroll
        for (int ni = 0; ni < 2; ++ni) acc[mi][ni] = (f32x4){0.f, 0.f, 0.f, 0.f};

    for (int k0 = kbeg; k0 < kend; k0 += 64) {
        __syncthreads();
#pragma unroll
        for (int it = 0; it < 2; ++it) {
            int idx = tid + it * 256;
            int row = idx >> 3, kgi = idx & 7;
            if (ATANH) {
                const float* sa = (const float*)A + (size_t)(m0 + row) * lda + k0 + kgi * 8;
                float4 a0 = *reinterpret_cast<const float4*>(sa);
                float4 a1 = *reinterpret_cast<const float4*>(sa + 4);
                bf16x8 u;
                u[0] = (__bf16)ftanh(a0.x); u[1] = (__bf16)ftanh(a0.y);
                u[2] = (__bf16)ftanh(a0.z); u[3] = (__bf16)ftanh(a0.w);
                u[4] = (__bf16)ftanh(a1.x); u[5] = (__bf16)ftanh(a1.y);
                u[6] = (__bf16)ftanh(a1.z); u[7] = (__bf16)ftanh(a1.w);
                *reinterpret_cast<bf16x8*>(&As[row * 72 + kgi * 8]) = u;
            } else {
                int4 va = *reinterpret_cast<const int4*>(
                    (const __bf16*)A + (size_t)(m0 + row) * lda + k0 + kgi * 8);
                *reinterpret_cast<int4*>(&As[row * 72 + kgi * 8]) = va;
            }
            int4 vb = *reinterpret_cast<const int4*>(B + (size_t)(n0 + row) * ldb + k0 + kgi * 8);
            *reinterpret_cast<int4*>(&Bs[row * 72 + kgi * 8]) = vb;
        }
        __syncthreads();
#pragma unroll
        for (int ks = 0; ks < 2; ++ks) {
            bf16x8 a[2], bb[2];
#pragma unroll
            for (int mi = 0; mi < 2; ++mi)
                a[mi] = *reinterpret_cast<const bf16x8*>(
                    &As[(w0 * 32 + mi * 16 + l15) * 72 + ks * 32 + quad * 8]);
#pragma unroll
            for (int ni = 0; ni < 2; ++ni)
                bb[ni] = *reinterpret_cast<const bf16x8*>(
                    &Bs[(w1 * 32 + ni * 16 + l15) * 72 + ks * 32 + quad * 8]);
#pragma unroll
            for (int mi = 0; mi < 2; ++mi)
#pragma unroll
                for (int ni = 0; ni < 2; ++ni)
                    acc[mi][ni] = __builtin_amdgcn_mfma_f32_16x16x32_bf16(
                        a[mi], bb[ni], acc[mi][ni], 0, 0, 0);
        }
    }

#pragma unroll
    for (int mi = 0; mi < 2; ++mi)
#pragma unroll
        for (int ni = 0; ni < 2; ++ni) {
            int col = n0 + w1 * 32 + ni * 16 + l15;
#pragma unroll
            for (int r = 0; r < 4; ++r) {
                int row = m0 + w0 * 32 + mi * 16 + quad * 4 + r;
                float bsv = (BMODE == 0) ? bias[col]
                          : (BMODE == 1) ? bias[(row & 63) * 1024 + col] : 0.f;
                if (ATOMIC) {
                    float v = acc[mi][ni][r] + (blockIdx.z == 0 ? bsv : 0.f);
                    atomicAdd((float*)Cout + (size_t)row * ldc + col, v);
                } else {
                    float v = acc[mi][ni][r] + bsv;
                    if (ACT) v = ftanh(v);
                    if (OUTBF) ((__bf16*)Cout)[(size_t)row * ldc + col] = (__bf16)v;
                    else       ((float*)Cout)[(size_t)row * ldc + col] = v;
                }
            }
        }
}

// ---------------- conv: e-chunk + p-half partials ----------------
template <int KW>
__device__ __forceinline__ void conv_body(
    const float* __restrict__ x, const float* __restrict__ wt,
    float* __restrict__ part, int b, int chunk, int bi_part, int pbase, float* xs)
{
    const int tid = threadIdx.x;
    const int f = tid & 127, esub = tid >> 7;
    const int e0 = chunk * 64;

#pragma unroll
    for (int it = 0; it < 16; ++it) {
        int idx = tid + it * 256;
        int e = idx & 63, p = idx >> 6;
        xs[e * 72 + p] = x[(size_t)(b * 64 + p) * 256 + e0 + e];
    }
    __syncthreads();

    float acc[32];
#pragma unroll
    for (int p = 0; p < 32; ++p) acc[p] = 0.f;

    for (int ei = 0; ei < 32; ++ei) {
        const int eL = esub * 32 + ei;
        float wreg[KW];
#pragma unroll
        for (int i = 0; i < KW; ++i)
            wreg[i] = wt[(size_t)((e0 + eL) * KW + i) * 128 + f];
        float xv[36];
#pragma unroll
        for (int k4 = 0; k4 < 9; ++k4) {
            float4 v = *reinterpret_cast<const float4*>(&xs[eL * 72 + pbase + k4 * 4]);
            xv[k4 * 4 + 0] = v.x; xv[k4 * 4 + 1] = v.y;
            xv[k4 * 4 + 2] = v.z; xv[k4 * 4 + 3] = v.w;
        }
#pragma unroll
        for (int i = 0; i < KW; ++i)
#pragma unroll
            for (int p = 0; p < 32; ++p)
                acc[p] = fmaf(wreg[i], xv[p + i], acc[p]);
    }

    float* op = part + ((size_t)(bi_part * 2 + esub)) * 8192 + f;
#pragma unroll
    for (int p = 0; p < 32; ++p) op[(pbase + p) * 128] = acc[p];
}

__global__ __launch_bounds__(256) void conv_partial_kernel(
    const float* __restrict__ x,
    const float* __restrict__ wt0, const float* __restrict__ wt1,
    const float* __restrict__ wt2, float* __restrict__ part)
{
    __shared__ float xs[64 * 72];
    const int bi = blockIdx.x;            // kw*64 + b*8 + chunk*2 + phalf
    const int kw = bi >> 6, b = (bi >> 3) & 7, chunk = (bi >> 1) & 3;
    const int pbase = (bi & 1) * 32;
    const int bi_part = kw * 32 + b * 4 + chunk;
    if (kw == 0)      conv_body<5>(x, wt0, part, b, chunk, bi_part, pbase, xs);
    else if (kw == 1) conv_body<4>(x, wt1, part, b, chunk, bi_part, pbase, xs);
    else              conv_body<3>(x, wt2, part, b, chunk, bi_part, pbase, xs);
}

// p-parallel reduce: 192 blocks = kw(3) x b(8) x pc(8); int-bits atomicMax is
// valid for floats >= 0 (relu floor); cnn pre-zeroed in cvt.
__global__ __launch_bounds__(128) void reduce_pool_kernel(
    const float* __restrict__ part,
    const float* __restrict__ b0, const float* __restrict__ b1,
    const float* __restrict__ b2, float* __restrict__ cnn)
{
    const int bi = blockIdx.x;
    const int kw = bi >> 6, b = (bi >> 3) & 7, pc = bi & 7;
    const int f = threadIdx.x;
    const int KW = 5 - kw, P = 64 - KW + 1;
    const float bias = (kw == 0 ? b0 : kw == 1 ? b1 : b2)[f];
    float mx = 0.f;                        // relu floor
#pragma unroll
    for (int pl = 0; pl < 8; ++pl) {
        int p = pc * 8 + pl;
        if (p < P) {
            float s = 0.f;
#pragma unroll
            for (int c4 = 0; c4 < 4; ++c4)
#pragma unroll
                for (int es = 0; es < 2; ++es)
                    s += part[((size_t)((kw * 32 + b * 4 + c4) * 2 + es)) * 8192 + p * 128 + f];
            s += bias;
            mx = fmaxf(mx, s);
        }
    }
    if (mx > 0.f)
        atomicMax((int*)(cnn + b * 384 + kw * 128 + f), __float_as_int(mx));
}

__global__ void final_kernel(const float* __restrict__ cnn, const float* __restrict__ Wc,
                             const float* __restrict__ bc, float* __restrict__ out)
{
    int o = threadIdx.x;
    if (o >= 320) return;
    int b = o / 40, t = o - b * 40;
    float s = bc[t];
    for (int i = 0; i < 384; ++i) s += cnn[b * 384 + i] * Wc[t * 384 + i];
    out[o] = s;
}

extern "C" void kernel_launch(void* const* d_in, const int* in_sizes, int n_in,
                              void* d_out, int out_size, void* d_ws, size_t ws_size,
                              hipStream_t stream)
{
    (void)in_sizes; (void)n_in; (void)out_size;
    const float* q    = (const float*)d_in[0];
    const float* ctx  = (const float*)d_in[1];
    const int*   mask = (const int*)d_in[2];
    const float* Wh   = (const float*)d_in[3];
    const float* bh   = (const float*)d_in[4];
    const float* Wv   = (const float*)d_in[5];
    const float* bv   = (const float*)d_in[6];
    const float* Wl   = (const float*)d_in[7];
    const float* bl   = (const float*)d_in[8];
    const float* cw0  = (const float*)d_in[9];
    const float* cb0  = (const float*)d_in[10];
    const float* cw1  = (const float*)d_in[11];
    const float* cb1  = (const float*)d_in[12];
    const float* cw2  = (const float*)d_in[13];
    const float* cb2  = (const float*)d_in[14];
    const float* Wc   = (const float*)d_in[15];
    const float* bc   = (const float*)d_in[16];

    float* ws   = (float*)d_ws;
    float* Apre = ws;                     // 65536
    float* g    = Apre + 65536;           // 131072 (unused, kept for layout)
    float* x    = g + 131072;             // 131072
    float* cnn  = x + 131072;             // 3072
    float* part = cnn + 3072;             // 1572864 (96*2*64*128)
    float* wt0  = part + 1572864;         // 163840
    float* wt1  = wt0 + 163840;           // 131072
    float* wt2  = wt1 + 131072;           // 98304
    __bf16* bfb    = (__bf16*)(wt2 + 98304);
    __bf16* Whbf   = bfb;                 // 1048576
    __bf16* Wlbf   = bfb + 1048576;       // 262144
    __bf16* feat2b = bfb + 1310720;       // 393216 (512*768)
    float*  gsc    = (float*)(bfb + 2228224); // 65536 f (scores scratch)
    // Whbf_t + Bpre alias `part` (disjoint lifetimes vs conv's use of part).
    // h2pre aliases Bpre (Bpre dead after attn_mfma; h2pre zeroed in attn_tail).
    __bf16* Whbf_t = (__bf16*)part;       // 524288 bf16
    float*  Bpre   = (float*)(Whbf_t + 524288); // 1048576 f
    float*  h2pre  = Bpre;                // 524288 f (aliases Bpre)
    // base usage ends at byte 13905920. Ubf (67MB) appended when ws allows.
    const size_t UBF_OFF = 13905920;      // 16B-aligned
    const size_t UBF_BYTES = (size_t)33554432 * 2;
    const bool bigws = ws_size >= UBF_OFF + UBF_BYTES;
    __bf16* Ubf = (__bf16*)((char*)d_ws + UBF_OFF);

    dim3 blk(256);
    // cvt: 0-15 Apre GEMM, 16-271 Bpre GEMM, 272-2907 conversions,
    //      2908-4955 Ubf materialize (bigws only)
    cvt_kernel<<<bigws ? 4956 : 2908, blk, 0, stream>>>(
        Wh, Wl, ctx, cw0, cw1, cw2, q, bh, Apre, x, Bpre,
        Whbf, Whbf_t, Wlbf, wt0, wt1, wt2, gsc, cnn, Ubf);
    // attn MFMA (K=512) + score atomics
    if (bigws)
        attn_mfma_u_kernel<<<2048, dim3(512), 0, stream>>>(
            Ubf, Whbf_t, Wv, Apre, Bpre, gsc);
    else
        attn_mfma_kernel<<<2048, dim3(512), 0, stream>>>(
            q, ctx, Whbf_t, Wv, Apre, Bpre, gsc);
    // softmax/g tail (writes feat2 + zeroes h2pre)
    attn_tail_kernel<<<512, blk, 0, stream>>>(ctx, mask, bv, gsc, q, feat2b, h2pre);
    // h2pre = feat2 @ Wh[:,256:]^T + Apre (K-split atomic, fp32; tanh deferred)
    mfma_gemm_kernel<0, 0, 1, 1, 0><<<dim3(16, 8, 2), blk, 0, stream>>>(
        feat2b, 768, Whbf + 256, 1024, Apre, h2pre, 768, 1024);
    // x = tanh(h2pre) @ Wl^T + bl (K-split atomic; tanh+cvt in A-staging)
    mfma_gemm_kernel<0, 0, 0, 1, 1><<<dim3(4, 8, 4), blk, 0, stream>>>(
        h2pre, 1024, Wlbf, 1024, bl, x, 1024, 256);
    // conv partials + reduce/pool + final FC
    conv_partial_kernel<<<192, blk, 0, stream>>>(x, wt0, wt1, wt2, part);
    reduce_pool_kernel<<<192, dim3(128), 0, stream>>>(part, cb0, cb1, cb2, cnn);
    final_kernel<<<1, 320, 0, stream>>>(cnn, Wc, bc, (float*)d_out);
}

// Round 14
// 261.270 us; speedup vs baseline: 1.0464x; 1.0464x over previous
//
#include <hip/hip_runtime.h>
#include <math.h>

// B=8, C=64, T=128, E=256, 4E=1024, TYPE_NUM=40, NF=128
// v20 = v19 + XCD-chunked blockIdx swizzle on attn_mfma_u (T1):
//   wid = (bid%8)*256 + bid/8 -> each XCD processes contiguous work-ids, and
//   the 8 ng blocks of one cpair run back-to-back on the SAME XCD, so the
//   cpair's 256KB of U tiles stay L2-resident (was: 8 ngs round-robined over
//   8 XCDs, each refetching U -> FETCH 267MB = 4x Ubf).
//   h_pre[b,c,t,:] = Apre[c,:] + Bpre[b*128+t,:] + [|q-ctx|, q*ctx] @ Wh[:,512:]^T

typedef __bf16 bf16x8 __attribute__((ext_vector_type(8)));
typedef float  f32x4  __attribute__((ext_vector_type(4)));

__device__ __forceinline__ float ftanh(float v) {
    float t = __expf(2.f * v);
    return 1.f - 2.f * __builtin_amdgcn_rcpf(t + 1.f);
}

// async 16B/lane global->LDS copy: lds dest must be wave-uniform; lane i lands
// at l + i*16B. g is per-lane.
__device__ __forceinline__ void gld_lds16(const __bf16* g, __bf16* l) {
    __builtin_amdgcn_global_load_lds(
        (const __attribute__((address_space(1))) void*)g,
        (__attribute__((address_space(3))) void*)l, 16, 0, 0);
}

__device__ __forceinline__ bf16x8 cvt8(float4 f0, float4 f1) {
    bf16x8 u;
    u[0] = (__bf16)f0.x; u[1] = (__bf16)f0.y; u[2] = (__bf16)f0.z; u[3] = (__bf16)f0.w;
    u[4] = (__bf16)f1.x; u[5] = (__bf16)f1.y; u[6] = (__bf16)f1.z; u[7] = (__bf16)f1.w;
    return u;
}

// ---------------- cvt + fused Apre GEMM + fused Bpre GEMM + U-materialize -------
// blocks 0-15:     Apre = q @ Wh^T + bh  (fp32 exact; M=64,N=1024,K=256)
// blocks 16-271:   Bpre = bf16(ctx) @ bf16(Wh[:,256:512])^T (inline cvt staging)
// blocks 272-2907: conversions / zero-init (idx-driven)
// blocks >=2908:   Ubf materialize
__global__ __launch_bounds__(256) void cvt_kernel(
    const float* __restrict__ Wh, const float* __restrict__ Wl,
    const float* __restrict__ ctx,
    const float* __restrict__ cw0, const float* __restrict__ cw1,
    const float* __restrict__ cw2,
    const float* __restrict__ q, const float* __restrict__ bh,
    float* __restrict__ Apre, float* __restrict__ x, float* __restrict__ Bpre,
    __bf16* __restrict__ Whbf, __bf16* __restrict__ Whbf_t,
    __bf16* __restrict__ Wlbf,
    float* __restrict__ wt0, float* __restrict__ wt1,
    float* __restrict__ wt2, float* __restrict__ gsc,
    float* __restrict__ cnn, __bf16* __restrict__ Ubf)
{
    __shared__ __align__(16) char smem[18432];
    const int bx = blockIdx.x;
    const int tid = threadIdx.x;

    if (bx >= 2908) {
        // ---- Ubf materialize: thread = (bc, trow, kg); 524288 threads ----
        int idx2 = (bx - 2908) * 256 + tid;      // < 524288
        int bc = idx2 >> 10;                     // 0..511
        int rem = idx2 & 1023;
        int trow = rem >> 3, kg = rem & 7;
        int b = bc >> 6, c = bc & 63;
        int gs = kg ^ (trow & 7);
#pragma unroll
        for (int ec = 0; ec < 4; ++ec) {
            int eb = ec * 64 + kg * 8;
            const float* cp = ctx + (size_t)(b * 128 + trow) * 256 + eb;
            float4 c0 = *reinterpret_cast<const float4*>(cp);
            float4 c1 = *reinterpret_cast<const float4*>(cp + 4);
            const float* qp = q + (size_t)c * 256 + eb;
            float4 q0 = *reinterpret_cast<const float4*>(qp);
            float4 q1 = *reinterpret_cast<const float4*>(qp + 4);
            float cv[8] = {c0.x, c0.y, c0.z, c0.w, c1.x, c1.y, c1.z, c1.w};
            float qv[8] = {q0.x, q0.y, q0.z, q0.w, q1.x, q1.y, q1.z, q1.w};
            bf16x8 ua, um;
#pragma unroll
            for (int i = 0; i < 8; ++i) {
                ua[i] = (__bf16)fabsf(qv[i] - cv[i]);
                um[i] = (__bf16)(qv[i] * cv[i]);
            }
            *reinterpret_cast<bf16x8*>(
                Ubf + (((size_t)(bc * 8 + ec) * 128 + trow) * 8 + gs) * 8) = ua;
            *reinterpret_cast<bf16x8*>(
                Ubf + (((size_t)(bc * 8 + 4 + ec) * 128 + trow) * 8 + gs) * 8) = um;
        }
        return;
    }

    if (bx < 16) {
        // ---- Apre GEMM: C[m,n] = sum_k q[m,k]*Wh[n,k] + bh[n] ----
        float (*As)[68] = reinterpret_cast<float(*)[68]>(smem);
        float (*Bs)[68] = reinterpret_cast<float(*)[68]>(smem + 4352);
        const int n0 = bx * 64;
        const int tm = tid >> 4, tn = tid & 15;
        const int lr = tid >> 2;
        const int lc = (tid & 3) * 4;

        float acc[4][4];
#pragma unroll
        for (int i = 0; i < 4; ++i)
#pragma unroll
            for (int j = 0; j < 4; ++j) acc[i][j] = 0.f;

        for (int k0 = 0; k0 < 256; k0 += 16) {
            float4 av = *reinterpret_cast<const float4*>(q + (size_t)lr * 256 + k0 + lc);
            float4 bv = *reinterpret_cast<const float4*>(Wh + (size_t)(n0 + lr) * 1024 + k0 + lc);
            As[lc + 0][lr] = av.x; As[lc + 1][lr] = av.y; As[lc + 2][lr] = av.z; As[lc + 3][lr] = av.w;
            Bs[lc + 0][lr] = bv.x; Bs[lc + 1][lr] = bv.y; Bs[lc + 2][lr] = bv.z; Bs[lc + 3][lr] = bv.w;
            __syncthreads();
#pragma unroll
            for (int kk = 0; kk < 16; ++kk) {
                float4 a = *reinterpret_cast<const float4*>(&As[kk][tm * 4]);
                float4 b = *reinterpret_cast<const float4*>(&Bs[kk][tn * 4]);
                float ar[4] = {a.x, a.y, a.z, a.w};
                float br[4] = {b.x, b.y, b.z, b.w};
#pragma unroll
                for (int i = 0; i < 4; ++i)
#pragma unroll
                    for (int j = 0; j < 4; ++j) acc[i][j] += ar[i] * br[j];
            }
            __syncthreads();
        }

#pragma unroll
        for (int i = 0; i < 4; ++i) {
            int m = tm * 4 + i;
            float vals[4];
#pragma unroll
            for (int j = 0; j < 4; ++j) vals[j] = acc[i][j] + bh[n0 + tn * 4 + j];
            float4 o; o.x = vals[0]; o.y = vals[1]; o.z = vals[2]; o.w = vals[3];
            *reinterpret_cast<float4*>(Apre + (size_t)m * 1024 + n0 + tn * 4) = o;
        }
        return;
    }

    if (bx < 272) {
        // ---- Bpre GEMM (MFMA, inline fp32->bf16 staging) ----
        __bf16* As = reinterpret_cast<__bf16*>(smem);
        __bf16* Bs = As + 64 * 72;
        const int bid = bx - 16;
        const int m0 = (bid >> 4) * 64, n0 = (bid & 15) * 64;
        const int wave = tid >> 6, lane = tid & 63;
        const int w0 = wave >> 1, w1 = wave & 1;
        const int l15 = lane & 15, quad = lane >> 4;

        f32x4 acc[2][2];
#pragma unroll
        for (int mi = 0; mi < 2; ++mi)
#pragma unroll
            for (int ni = 0; ni < 2; ++ni) acc[mi][ni] = (f32x4){0.f, 0.f, 0.f, 0.f};

        for (int k0 = 0; k0 < 256; k0 += 64) {
            __syncthreads();
#pragma unroll
            for (int it = 0; it < 2; ++it) {
                int idx = tid + it * 256;
                int row = idx >> 3, kgi = idx & 7;
                const float* sa = ctx + (size_t)(m0 + row) * 256 + k0 + kgi * 8;
                float4 a0 = *reinterpret_cast<const float4*>(sa);
                float4 a1 = *reinterpret_cast<const float4*>(sa + 4);
                *reinterpret_cast<bf16x8*>(&As[row * 72 + kgi * 8]) = cvt8(a0, a1);
                const float* sb = Wh + (size_t)(n0 + row) * 1024 + 256 + k0 + kgi * 8;
                float4 b0 = *reinterpret_cast<const float4*>(sb);
                float4 b1 = *reinterpret_cast<const float4*>(sb + 4);
                *reinterpret_cast<bf16x8*>(&Bs[row * 72 + kgi * 8]) = cvt8(b0, b1);
            }
            __syncthreads();
#pragma unroll
            for (int ks = 0; ks < 2; ++ks) {
                bf16x8 a[2], bb[2];
#pragma unroll
                for (int mi = 0; mi < 2; ++mi)
                    a[mi] = *reinterpret_cast<const bf16x8*>(
                        &As[(w0 * 32 + mi * 16 + l15) * 72 + ks * 32 + quad * 8]);
#pragma unroll
                for (int ni = 0; ni < 2; ++ni)
                    bb[ni] = *reinterpret_cast<const bf16x8*>(
                        &Bs[(w1 * 32 + ni * 16 + l15) * 72 + ks * 32 + quad * 8]);
#pragma unroll
                for (int mi = 0; mi < 2; ++mi)
#pragma unroll
                    for (int ni = 0; ni < 2; ++ni)
                        acc[mi][ni] = __builtin_amdgcn_mfma_f32_16x16x32_bf16(
                            a[mi], bb[ni], acc[mi][ni], 0, 0, 0);
            }
        }

#pragma unroll
        for (int mi = 0; mi < 2; ++mi)
#pragma unroll
            for (int ni = 0; ni < 2; ++ni) {
                int col = n0 + w1 * 32 + ni * 16 + l15;
#pragma unroll
                for (int r = 0; r < 4; ++r) {
                    int row = m0 + w0 * 32 + mi * 16 + quad * 4 + r;
                    Bpre[(size_t)row * 1024 + col] = acc[mi][ni][r];
                }
            }
        return;
    }

    int idx = (bx - 272) * 256 + tid;            // < 674816
    if (idx < 131072) {                          // Whbf flat
        const float* s = Wh + (size_t)idx * 8;
        float4 f0 = *reinterpret_cast<const float4*>(s);
        float4 f1 = *reinterpret_cast<const float4*>(s + 4);
        *reinterpret_cast<bf16x8*>(Whbf + (size_t)idx * 8) = cvt8(f0, f1);
        return;
    }
    if (idx < 196608) {                          // Whbf_t 65536 granules
        int di = idx - 131072;
        int ng = di >> 13, kc = (di >> 10) & 7;
        int row = (di >> 3) & 127, kgp = di & 7;
        int kg = kgp ^ (row & 7);
        const float* s = Wh + (size_t)(ng * 128 + row) * 1024 + 512 + kc * 64 + kg * 8;
        float4 f0 = *reinterpret_cast<const float4*>(s);
        float4 f1 = *reinterpret_cast<const float4*>(s + 4);
        *reinterpret_cast<bf16x8*>(Whbf_t + (size_t)di * 8) = cvt8(f0, f1);
        return;
    }
    if (idx < 229376) {                          // Wlbf 32768 granules
        int di = idx - 196608;
        const float* s = Wl + (size_t)di * 8;
        float4 f0 = *reinterpret_cast<const float4*>(s);
        float4 f1 = *reinterpret_cast<const float4*>(s + 4);
        *reinterpret_cast<bf16x8*>(Wlbf + (size_t)di * 8) = cvt8(f0, f1);
        return;
    }
    if (idx < 393216) {
        int j = idx - 229376; int f = j & 127, rest = j >> 7;
        int i = rest % 5, e = rest / 5;
        wt0[j] = cw0[(size_t)(f * 256 + e) * 5 + i]; return;
    }
    if (idx < 524288) {
        int j = idx - 393216; int f = j & 127, rest = j >> 7;
        int i = rest & 3, e = rest >> 2;
        wt1[j] = cw1[(size_t)(f * 256 + e) * 4 + i]; return;
    }
    if (idx < 622592) {
        int j = idx - 524288; int f = j & 127, rest = j >> 7;
        int i = rest % 3, e = rest / 3;
        wt2[j] = cw2[(size_t)(f * 256 + e) * 3 + i]; return;
    }
    if (idx < 638976) {                          // gsc zero (float4)
        int di = idx - 622592;
        reinterpret_cast<float4*>(gsc)[di] = (float4){0.f, 0.f, 0.f, 0.f};
        return;
    }
    if (idx < 642048) { cnn[idx - 638976] = 0.f; return; }
    if (idx < 674816) {                          // x zero (float4)
        int di = idx - 642048;
        reinterpret_cast<float4*>(x)[di] = (float4){0.f, 0.f, 0.f, 0.f};
    }
}

// ---------------- attn v20 MFMA: all-async + XCD-chunked swizzle ----------------
__global__ __launch_bounds__(512, 4) void attn_mfma_u_kernel(
    const __bf16* __restrict__ Ubf,     // [512bc][8kc][128][8g] swizzled granules
    const __bf16* __restrict__ Whbf_t,  // tiled+swizzled bf16 W (abs+mul cols)
    const float* __restrict__ Wv,       // [1024]
    const float* __restrict__ Apre,     // [64][1024]  (q-part + b_hidden)
    const float* __restrict__ Bpre,     // [1024][1024] (ctx-part)
    float* __restrict__ gsc)            // [512][128] pre-zeroed
{
    __shared__ __bf16 Us[256 * 64];     // rows 0-127: c0, 128-255: c0+1
    __shared__ __bf16 Ws[128 * 64];
    __shared__ float sc[256];

    const int tid = threadIdx.x;
    // XCD-chunked swizzle (T1): block bid lands on XCD bid%8 (round-robin);
    // wid = (bid%8)*256 + bid/8 gives each XCD a contiguous wid chunk, so the
    // 8 ng blocks of one cpair run back-to-back on ONE XCD (U stays L2-hot).
    const int wid = (blockIdx.x & 7) * 256 + (blockIdx.x >> 3);
    const int cpair = wid >> 3, ng = wid & 7;
    const int b = cpair >> 5, c0 = (cpair & 31) * 2;
    const int wave = tid >> 6, lane = tid & 63;
    const int w1 = wave & 1, w0 = wave >> 1;     // w0: M quarter 0..3
    const int m0 = w0 * 64;
    const int l15 = lane & 15, quad = lane >> 4;
    const int swz = l15 & 7;            // row&7 for all our frag rows

    if (tid < 256) sc[tid] = 0.f;
    __syncthreads();

    const __bf16* ubase = Ubf + (size_t)(b * 64 + c0) * 65536;   // 8 kc * 8192

    f32x4 acc[4][4];
#pragma unroll
    for (int mi = 0; mi < 4; ++mi)
#pragma unroll
        for (int ni = 0; ni < 4; ++ni) acc[mi][ni] = (f32x4){0.f, 0.f, 0.f, 0.f};

    for (int kc = 0; kc < 8; ++kc) {
        __syncthreads();            // prior MFMA reads done before overwrite
        // ---- W tile: 1024 granules async, 128 per wave ----
        const __bf16* wtile = Whbf_t + (size_t)(ng * 8 + kc) * 8192;
        // ---- U tiles: c0 and c0+1, 1024 granules each ----
        const __bf16* ut0 = ubase + (size_t)kc * 8192;
        const __bf16* ut1 = ut0 + 65536;
#pragma unroll
        for (int it = 0; it < 2; ++it) {
            int gidx = wave * 128 + it * 64;   // + lane inside
            gld_lds16(wtile + (size_t)(gidx + lane) * 8, &Ws[gidx * 8]);
            gld_lds16(ut0 + (size_t)(gidx + lane) * 8, &Us[gidx * 8]);
            gld_lds16(ut1 + (size_t)(gidx + lane) * 8, &Us[8192 + gidx * 8]);
        }
        __syncthreads();            // drains vmcnt (async)
        // ---- MFMA on staged chunk ----
#pragma unroll
        for (int ks = 0; ks < 2; ++ks) {
            const int c8 = (((ks * 4 + quad) ^ swz)) * 8;
            bf16x8 a[4], bfr[4];
#pragma unroll
            for (int mi = 0; mi < 4; ++mi)
                a[mi] = *reinterpret_cast<const bf16x8*>(
                    &Us[(m0 + mi * 16 + l15) * 64 + c8]);
#pragma unroll
            for (int ni = 0; ni < 4; ++ni)
                bfr[ni] = *reinterpret_cast<const bf16x8*>(
                    &Ws[(w1 * 64 + ni * 16 + l15) * 64 + c8]);
#pragma unroll
            for (int mi = 0; mi < 4; ++mi)
#pragma unroll
                for (int ni = 0; ni < 4; ++ni)
                    acc[mi][ni] = __builtin_amdgcn_mfma_f32_16x16x32_bf16(
                        a[mi], bfr[ni], acc[mi][ni], 0, 0, 0);
        }
    }

    // ---- epilogue: h = ftanh(acc + Apre + Bpre), partial score = h . Wv ----
    const int jcol = ng * 128 + w1 * 64 + l15;
    const int c = c0 + (w0 >> 1);
    float av[4], wv[4];
#pragma unroll
    for (int ni = 0; ni < 4; ++ni) {
        av[ni] = Apre[(size_t)c * 1024 + jcol + ni * 16];
        wv[ni] = Wv[jcol + ni * 16];
    }
#pragma unroll
    for (int mi = 0; mi < 4; ++mi) {
        const int tb = (w0 & 1) * 64 + mi * 16 + quad * 4;   // t within 0..127
        float p[4];
#pragma unroll
        for (int r = 0; r < 4; ++r) {
            const float* bp = Bpre + (size_t)(b * 128 + tb + r) * 1024 + jcol;
            float s = 0.f;
#pragma unroll
            for (int ni = 0; ni < 4; ++ni)
                s += ftanh(acc[mi][ni][r] + av[ni] + bp[ni * 16]) * wv[ni];
            p[r] = s;
        }
#pragma unroll
        for (int off = 1; off < 16; off <<= 1)
#pragma unroll
            for (int r = 0; r < 4; ++r) p[r] += __shfl_xor(p[r], off, 16);
        if (l15 == 0) {
#pragma unroll
            for (int r = 0; r < 4; ++r)
                atomicAdd(&sc[(w0 >> 1) * 128 + tb + r], p[r]);
        }
    }
    __syncthreads();

    // flush partial scores (8 ng blocks add into gsc)
    if (tid < 256) atomicAdd(&gsc[(size_t)(b * 64 + c0) * 128 + tid], sc[tid]);
}

// ---------------- attn tail: softmax + g, fused feat2 output + h2pre zero ------
__global__ __launch_bounds__(256) void attn_tail_kernel(
    const float* __restrict__ ctx, const int* __restrict__ mask,
    const float* __restrict__ bv, const float* __restrict__ gsc,
    const float* __restrict__ q, __bf16* __restrict__ feat2,
    float* __restrict__ h2pre)
{
    __shared__ float sc[128];
    __shared__ float red;
    const int tid = threadIdx.x;
    const int bc = blockIdx.x, b = bc >> 6, c = bc & 63;

    // zero h2pre for the K-split atomic GEMM (512*256 float4 = 524288 floats)
    reinterpret_cast<float4*>(h2pre)[(size_t)bc * 256 + tid] =
        (float4){0.f, 0.f, 0.f, 0.f};

    if (tid < 128) {
        float s = gsc[(size_t)bc * 128 + tid] + bv[0];
        if (mask[b * 128 + tid] < 1) s = -1e10f;
        sc[tid] = s;
    }
    __syncthreads();
    if (tid < 64) {
        float m = fmaxf(sc[tid], sc[tid + 64]);
        for (int off = 32; off; off >>= 1) m = fmaxf(m, __shfl_xor(m, off, 64));
        if (tid == 0) red = m;
    }
    __syncthreads();
    const float mx = red;
    if (tid < 128) sc[tid] = __expf(sc[tid] - mx);
    __syncthreads();
    if (tid < 64) {
        float s = sc[tid] + sc[tid + 64];
        for (int off = 32; off; off >>= 1) s += __shfl_xor(s, off, 64);
        if (tid == 0) red = s;
    }
    __syncthreads();
    const float inv = 1.f / red;

    float gv = 0.f;
#pragma unroll 16
    for (int t = 0; t < 128; ++t) gv += sc[t] * ctx[(size_t)(b * 128 + t) * 256 + tid];
    gv *= inv;
    const float qv = q[(size_t)c * 256 + tid];
    __bf16* o = feat2 + (size_t)bc * 768 + tid;
    o[0]   = (__bf16)gv;
    o[256] = (__bf16)fabsf(qv - gv);
    o[512] = (__bf16)(qv * gv);
}

// ---------------- bf16 MFMA GEMM: C = act(A @ B^T + bias), 64x64 tile ----------------
// BMODE 0: bias[col]; BMODE 1: bias[(row&63)*1024 + col]; BMODE 2: no bias
// ATOMIC 1: K split over blockIdx.z; atomicAdd into fp32 Cout (pre-zeroed);
//           bias added by z==0 only. Requires OUTBF=0, ACT=0.
// ATANH 1:  A is fp32; staging applies ftanh then converts to bf16.
template <int ACT, int OUTBF, int BMODE, int ATOMIC, int ATANH>
__global__ __launch_bounds__(256) void mfma_gemm_kernel(
    const void* __restrict__ A, int lda,
    const __bf16* __restrict__ B, int ldb,
    const float* __restrict__ bias, void* __restrict__ Cout,
    int K, int ldc)
{
    __shared__ __bf16 As[64 * 72];
    __shared__ __bf16 Bs[64 * 72];
    const int tid = threadIdx.x;
    const int wave = tid >> 6, lane = tid & 63;
    const int w0 = wave >> 1, w1 = wave & 1;
    const int l15 = lane & 15, quad = lane >> 4;
    const int m0 = blockIdx.y * 64, n0 = blockIdx.x * 64;

    int kbeg = 0, kend = K;
    if (ATOMIC) {
        int kchunk = K / gridDim.z;
        kbeg = blockIdx.z * kchunk;
        kend = kbeg + kchunk;
    }

    f32x4 acc[2][2];
#pragma unroll
    for (int mi = 0; mi < 2; ++mi)
#pragma unroll
        for (int ni = 0; ni < 2; ++ni) acc[mi][ni] = (f32x4){0.f, 0.f, 0.f, 0.f};

    for (int k0 = kbeg; k0 < kend; k0 += 64) {
        __syncthreads();
#pragma unroll
        for (int it = 0; it < 2; ++it) {
            int idx = tid + it * 256;
            int row = idx >> 3, kgi = idx & 7;
            if (ATANH) {
                const float* sa = (const float*)A + (size_t)(m0 + row) * lda + k0 + kgi * 8;
                float4 a0 = *reinterpret_cast<const float4*>(sa);
                float4 a1 = *reinterpret_cast<const float4*>(sa + 4);
                bf16x8 u;
                u[0] = (__bf16)ftanh(a0.x); u[1] = (__bf16)ftanh(a0.y);
                u[2] = (__bf16)ftanh(a0.z); u[3] = (__bf16)ftanh(a0.w);
                u[4] = (__bf16)ftanh(a1.x); u[5] = (__bf16)ftanh(a1.y);
                u[6] = (__bf16)ftanh(a1.z); u[7] = (__bf16)ftanh(a1.w);
                *reinterpret_cast<bf16x8*>(&As[row * 72 + kgi * 8]) = u;
            } else {
                int4 va = *reinterpret_cast<const int4*>(
                    (const __bf16*)A + (size_t)(m0 + row) * lda + k0 + kgi * 8);
                *reinterpret_cast<int4*>(&As[row * 72 + kgi * 8]) = va;
            }
            int4 vb = *reinterpret_cast<const int4*>(B + (size_t)(n0 + row) * ldb + k0 + kgi * 8);
            *reinterpret_cast<int4*>(&Bs[row * 72 + kgi * 8]) = vb;
        }
        __syncthreads();
#pragma unroll
        for (int ks = 0; ks < 2; ++ks) {
            bf16x8 a[2], bb[2];
#pragma unroll
            for (int mi = 0; mi < 2; ++mi)
                a[mi] = *reinterpret_cast<const bf16x8*>(
                    &As[(w0 * 32 + mi * 16 + l15) * 72 + ks * 32 + quad * 8]);
#pragma unroll
            for (int ni = 0; ni < 2; ++ni)
                bb[ni] = *reinterpret_cast<const bf16x8*>(
                    &Bs[(w1 * 32 + ni * 16 + l15) * 72 + ks * 32 + quad * 8]);
#pragma unroll
            for (int mi = 0; mi < 2; ++mi)
#pragma unroll
                for (int ni = 0; ni < 2; ++ni)
                    acc[mi][ni] = __builtin_amdgcn_mfma_f32_16x16x32_bf16(
                        a[mi], bb[ni], acc[mi][ni], 0, 0, 0);
        }
    }

#pragma unroll
    for (int mi = 0; mi < 2; ++mi)
#pragma unroll
        for (int ni = 0; ni < 2; ++ni) {
            int col = n0 + w1 * 32 + ni * 16 + l15;
#pragma unroll
            for (int r = 0; r < 4; ++r) {
                int row = m0 + w0 * 32 + mi * 16 + quad * 4 + r;
                float bsv = (BMODE == 0) ? bias[col]
                          : (BMODE == 1) ? bias[(row & 63) * 1024 + col] : 0.f;
                if (ATOMIC) {
                    float v = acc[mi][ni][r] + (blockIdx.z == 0 ? bsv : 0.f);
                    atomicAdd((float*)Cout + (size_t)row * ldc + col, v);
                } else {
                    float v = acc[mi][ni][r] + bsv;
                    if (ACT) v = ftanh(v);
                    if (OUTBF) ((__bf16*)Cout)[(size_t)row * ldc + col] = (__bf16)v;
                    else       ((float*)Cout)[(size_t)row * ldc + col] = v;
                }
            }
        }
}

// ---------------- conv: e-chunk + p-half partials ----------------
template <int KW>
__device__ __forceinline__ void conv_body(
    const float* __restrict__ x, const float* __restrict__ wt,
    float* __restrict__ part, int b, int chunk, int bi_part, int pbase, float* xs)
{
    const int tid = threadIdx.x;
    const int f = tid & 127, esub = tid >> 7;
    const int e0 = chunk * 64;

#pragma unroll
    for (int it = 0; it < 16; ++it) {
        int idx = tid + it * 256;
        int e = idx & 63, p = idx >> 6;
        xs[e * 72 + p] = x[(size_t)(b * 64 + p) * 256 + e0 + e];
    }
    __syncthreads();

    float acc[32];
#pragma unroll
    for (int p = 0; p < 32; ++p) acc[p] = 0.f;

    for (int ei = 0; ei < 32; ++ei) {
        const int eL = esub * 32 + ei;
        float wreg[KW];
#pragma unroll
        for (int i = 0; i < KW; ++i)
            wreg[i] = wt[(size_t)((e0 + eL) * KW + i) * 128 + f];
        float xv[36];
#pragma unroll
        for (int k4 = 0; k4 < 9; ++k4) {
            float4 v = *reinterpret_cast<const float4*>(&xs[eL * 72 + pbase + k4 * 4]);
            xv[k4 * 4 + 0] = v.x; xv[k4 * 4 + 1] = v.y;
            xv[k4 * 4 + 2] = v.z; xv[k4 * 4 + 3] = v.w;
        }
#pragma unroll
        for (int i = 0; i < KW; ++i)
#pragma unroll
            for (int p = 0; p < 32; ++p)
                acc[p] = fmaf(wreg[i], xv[p + i], acc[p]);
    }

    float* op = part + ((size_t)(bi_part * 2 + esub)) * 8192 + f;
#pragma unroll
    for (int p = 0; p < 32; ++p) op[(pbase + p) * 128] = acc[p];
}

__global__ __launch_bounds__(256) void conv_partial_kernel(
    const float* __restrict__ x,
    const float* __restrict__ wt0, const float* __restrict__ wt1,
    const float* __restrict__ wt2, float* __restrict__ part)
{
    __shared__ float xs[64 * 72];
    const int bi = blockIdx.x;            // kw*64 + b*8 + chunk*2 + phalf
    const int kw = bi >> 6, b = (bi >> 3) & 7, chunk = (bi >> 1) & 3;
    const int pbase = (bi & 1) * 32;
    const int bi_part = kw * 32 + b * 4 + chunk;
    if (kw == 0)      conv_body<5>(x, wt0, part, b, chunk, bi_part, pbase, xs);
    else if (kw == 1) conv_body<4>(x, wt1, part, b, chunk, bi_part, pbase, xs);
    else              conv_body<3>(x, wt2, part, b, chunk, bi_part, pbase, xs);
}

// p-parallel reduce: 192 blocks = kw(3) x b(8) x pc(8); int-bits atomicMax is
// valid for floats >= 0 (relu floor); cnn pre-zeroed in cvt.
__global__ __launch_bounds__(128) void reduce_pool_kernel(
    const float* __restrict__ part,
    const float* __restrict__ b0, const float* __restrict__ b1,
    const float* __restrict__ b2, float* __restrict__ cnn)
{
    const int bi = blockIdx.x;
    const int kw = bi >> 6, b = (bi >> 3) & 7, pc = bi & 7;
    const int f = threadIdx.x;
    const int KW = 5 - kw, P = 64 - KW + 1;
    const float bias = (kw == 0 ? b0 : kw == 1 ? b1 : b2)[f];
    float mx = 0.f;                        // relu floor
#pragma unroll
    for (int pl = 0; pl < 8; ++pl) {
        int p = pc * 8 + pl;
        if (p < P) {
            float s = 0.f;
#pragma unroll
            for (int c4 = 0; c4 < 4; ++c4)
#pragma unroll
                for (int es = 0; es < 2; ++es)
                    s += part[((size_t)((kw * 32 + b * 4 + c4) * 2 + es)) * 8192 + p * 128 + f];
            s += bias;
            mx = fmaxf(mx, s);
        }
    }
    if (mx > 0.f)
        atomicMax((int*)(cnn + b * 384 + kw * 128 + f), __float_as_int(mx));
}

__global__ void final_kernel(const float* __restrict__ cnn, const float* __restrict__ Wc,
                             const float* __restrict__ bc, float* __restrict__ out)
{
    int o = threadIdx.x;
    if (o >= 320) return;
    int b = o / 40, t = o - b * 40;
    float s = bc[t];
    for (int i = 0; i < 384; ++i) s += cnn[b * 384 + i] * Wc[t * 384 + i];
    out[o] = s;
}

extern "C" void kernel_launch(void* const* d_in, const int* in_sizes, int n_in,
                              void* d_out, int out_size, void* d_ws, size_t ws_size,
                              hipStream_t stream)
{
    (void)in_sizes; (void)n_in; (void)out_size;
    const float* q    = (const float*)d_in[0];
    const float* ctx  = (const float*)d_in[1];
    const int*   mask = (const int*)d_in[2];
    const float* Wh   = (const float*)d_in[3];
    const float* bh   = (const float*)d_in[4];
    const float* Wv   = (const float*)d_in[5];
    const float* bv   = (const float*)d_in[6];
    const float* Wl   = (const float*)d_in[7];
    const float* bl   = (const float*)d_in[8];
    const float* cw0  = (const float*)d_in[9];
    const float* cb0  = (const float*)d_in[10];
    const float* cw1  = (const float*)d_in[11];
    const float* cb1  = (const float*)d_in[12];
    const float* cw2  = (const float*)d_in[13];
    const float* cb2  = (const float*)d_in[14];
    const float* Wc   = (const float*)d_in[15];
    const float* bc   = (const float*)d_in[16];

    float* ws   = (float*)d_ws;
    float* Apre = ws;                     // 65536
    float* g    = Apre + 65536;           // 131072 (unused, kept for layout)
    float* x    = g + 131072;             // 131072
    float* cnn  = x + 131072;             // 3072
    float* part = cnn + 3072;             // 1572864 (96*2*64*128)
    float* wt0  = part + 1572864;         // 163840
    float* wt1  = wt0 + 163840;           // 131072
    float* wt2  = wt1 + 131072;           // 98304
    __bf16* bfb    = (__bf16*)(wt2 + 98304);
    __bf16* Whbf   = bfb;                 // 1048576
    __bf16* Wlbf   = bfb + 1048576;       // 262144
    __bf16* feat2b = bfb + 1310720;       // 393216 (512*768)
    float*  gsc    = (float*)(bfb + 2228224); // 65536 f (scores scratch)
    // Whbf_t + Bpre alias `part` (disjoint lifetimes vs conv's use of part).
    // h2pre aliases Bpre (Bpre dead after attn_mfma; h2pre zeroed in attn_tail).
    __bf16* Whbf_t = (__bf16*)part;       // 524288 bf16
    float*  Bpre   = (float*)(Whbf_t + 524288); // 1048576 f
    float*  h2pre  = Bpre;                // 524288 f (aliases Bpre)
    // base usage ends at byte 13905920. Ubf (67MB) appended when ws allows.
    const size_t UBF_OFF = 13905920;      // 16B-aligned
    const size_t UBF_BYTES = (size_t)33554432 * 2;
    const bool bigws = ws_size >= UBF_OFF + UBF_BYTES;
    __bf16* Ubf = (__bf16*)((char*)d_ws + UBF_OFF);

    dim3 blk(256);
    // cvt: 0-15 Apre GEMM, 16-271 Bpre GEMM, 272-2907 conversions,
    //      2908-4955 Ubf materialize (bigws only)
    cvt_kernel<<<bigws ? 4956 : 2908, blk, 0, stream>>>(
        Wh, Wl, ctx, cw0, cw1, cw2, q, bh, Apre, x, Bpre,
        Whbf, Whbf_t, Wlbf, wt0, wt1, wt2, gsc, cnn, Ubf);
    // attn MFMA (K=512) + score atomics (Ubf path requires bigws; the
    // harness workspace is >> 81MB so this is the active path)
    attn_mfma_u_kernel<<<2048, dim3(512), 0, stream>>>(
        Ubf, Whbf_t, Wv, Apre, Bpre, gsc);
    // softmax/g tail (writes feat2 + zeroes h2pre)
    attn_tail_kernel<<<512, blk, 0, stream>>>(ctx, mask, bv, gsc, q, feat2b, h2pre);
    // h2pre = feat2 @ Wh[:,256:]^T + Apre (K-split atomic, fp32; tanh deferred)
    mfma_gemm_kernel<0, 0, 1, 1, 0><<<dim3(16, 8, 2), blk, 0, stream>>>(
        feat2b, 768, Whbf + 256, 1024, Apre, h2pre, 768, 1024);
    // x = tanh(h2pre) @ Wl^T + bl (K-split atomic; tanh+cvt in A-staging)
    mfma_gemm_kernel<0, 0, 0, 1, 1><<<dim3(4, 8, 4), blk, 0, stream>>>(
        h2pre, 1024, Wlbf, 1024, bl, x, 1024, 256);
    // conv partials + reduce/pool + final FC
    conv_partial_kernel<<<192, blk, 0, stream>>>(x, wt0, wt1, wt2, part);
    reduce_pool_kernel<<<192, dim3(128), 0, stream>>>(part, cb0, cb1, cb2, cnn);
    final_kernel<<<1, 320, 0, stream>>>(cnn, Wc, bc, (float*)d_out);
}